// Round 5
// baseline (415.584 us; speedup 1.0000x reference)
//
#include <hip/hip_runtime.h>

using half8   = __attribute__((ext_vector_type(8))) _Float16;
using floatx4 = __attribute__((ext_vector_type(4))) float;

namespace {
constexpr int S = 196, D = 512, C = 1006, Cpad = 1024;
constexpr int CB = 16;      // block c-tile
constexpr int EBLK = 256;   // block e-tile
constexpr int BK = 32;      // k-chunk (16 chunks; 1 MFMA k-step each)
constexpr int NCH = D / BK; // 16
constexpr int TPB = 256;    // 4 waves; 3 blocks/CU
constexpr int SCH = 3;      // s-chunks 66/66/64 -> grid 768 = 3 blocks/CU
constexpr float KTANH = 2.885390082f;    // 2/ln2 folded into img staging
constexpr float INVK  = 0.34657359028f;  // ln2/2 to recover raw img

// ws layout
constexpr size_t W16_BYTES = (size_t)D * D * 2;               // 512 KB swizzled W
constexpr size_t LA_OFF    = W16_BYTES;
constexpr size_t SLICE_ELEMS = (size_t)2 * Cpad * D;
constexpr size_t SL_BYTES  = (size_t)SCH * SLICE_ELEMS * 4;   // 12 MB per set
constexpr size_t SLICE_NEED = LA_OFF + 2 * SL_BYTES;
constexpr size_t L_BYTES   = SLICE_ELEMS * 4;

// Pair-XOR swizzle for chunk-local tiles of (rows x 4 16B-segs):
// pair p=row>>1 spans 8 segs; seg q = (row&1)*4+j, XOR'd by p&7.
// Keeps r-pair contiguity (DMA-friendly, no pad) and spreads banks uniformly.
__device__ __forceinline__ int phys16(int row, int j) {
    int p = row >> 1;
    int q = ((((row & 1) << 2) | j) ^ (p & 7));
    return p * 8 + q;          // 16B units
}

__device__ __forceinline__ void gload16(const _Float16* g, _Float16* l) {
    __builtin_amdgcn_global_load_lds(
        (const __attribute__((address_space(1))) unsigned int*)g,
        (__attribute__((address_space(3))) unsigned int*)l, 16, 0, 0);
}

__device__ __forceinline__ _Float16 tanh_ps(float y) {
    // y = (2/ln2)*x; tanh(x) = 1 - 2/(exp2(y)+1); saturates correctly
    float e = __builtin_amdgcn_exp2f(y);
    return (_Float16)(1.0f - 2.0f * __builtin_amdgcn_rcpf(e + 1.0f));
}

// Pre-swizzle fc3_w into the exact per-chunk LDS image (16 chunks of 512 rows x 4 segs)
__global__ void prep_w16sw(const float* __restrict__ fw, _Float16* __restrict__ W16sw) {
    int id = blockIdx.x * blockDim.x + threadIdx.x;   // 32768 segs
    int kki = id >> 11;
    int rem = id & 2047;
    int r = rem >> 2, j = rem & 3;
    const float* src = fw + (size_t)r * D + kki * BK + j * 8;
    floatx4 v0 = *(const floatx4*)src;
    floatx4 v1 = *(const floatx4*)(src + 4);
    half8 h;
    h[0] = (_Float16)v0[0]; h[1] = (_Float16)v0[1];
    h[2] = (_Float16)v0[2]; h[3] = (_Float16)v0[3];
    h[4] = (_Float16)v1[0]; h[5] = (_Float16)v1[1];
    h[6] = (_Float16)v1[2]; h[7] = (_Float16)v1[3];
    *(half8*)&W16sw[((size_t)kki << 14) + (phys16(r, j) << 3)] = h;
}

__global__ __launch_bounds__(TPB, 3) void semdec_mfma(
    const float* __restrict__ img, const float* __restrict__ word,
    const _Float16* __restrict__ W16sw,
    float* __restrict__ lbase, float* __restrict__ abase, int use_slice)
{
    __shared__ __align__(16) _Float16 Wc[2][EBLK * BK];   // 2 x 16 KB
    __shared__ __align__(16) _Float16 Tc[2][4 * CB * BK]; // 2 x 4 KB
    __shared__ __align__(16) float imgS[4][D];            // 8 KB (pre-scaled by 2/ln2)
    // total 48 KB -> 3 blocks/CU

    const int ct = blockIdx.x;           // 0..63
    const int et = blockIdx.y & 1;
    const int b  = blockIdx.y >> 1;
    const int sc = blockIdx.z;           // 0..2

    const int tid  = threadIdx.x;
    const int lane = tid & 63;
    const int wv   = tid >> 6;           // wave 0..3: e-slot for MFMA, si for T-stage
    const int l15  = lane & 15;
    const int quad = lane >> 4;
    const int ciT  = lane & 15;          // T-stage c index
    const int jgT  = lane >> 4;          // T-stage 16B-seg (k sub-block)

    const int c0 = ct * CB;
    const int e0 = et * EBLK;

    int cgT = c0 + ciT; if (cgT > C - 1) cgT = C - 1;   // clamp pad rows
    const float* wordRow = word + (size_t)cgT * D;

    floatx4 lacc[4], aacc[4];            // 32 VGPR
    #pragma unroll
    for (int ej = 0; ej < 4; ++ej) {
        lacc[ej] = (floatx4){0.f, 0.f, 0.f, 0.f};
        aacc[ej] = (floatx4){0.f, 0.f, 0.f, 0.f};
    }

    const float* imgB = img + (size_t)b * S * D;
    const int s_base = sc * 66;
    const int npass = (sc < 2) ? 17 : 16;

    for (int pr = 0; pr < npass; ++pr) {
        const int s0 = s_base + pr * 4;
        const int slim = (pr == 16) ? 2 : 4;   // tail covers 2 s (extra rows in-range, discarded)

        __syncthreads();  // prior pass: imgS readers + last-chunk MFMA done
        #pragma unroll
        for (int it = 0; it < 2; ++it) {
            int sid = it * TPB + tid;
            int si = sid >> 7, pos = (sid & 127) << 2;
            floatx4 v = *(const floatx4*)&imgB[(size_t)(s0 + si) * D + pos];
            floatx4 sv = {v[0] * KTANH, v[1] * KTANH, v[2] * KTANH, v[3] * KTANH};
            *(floatx4*)&imgS[si][pos] = sv;
        }
        __syncthreads();  // imgS visible

        floatx4 acc[4][4];   // [si][ej] 64 AGPR
        #pragma unroll
        for (int si = 0; si < 4; ++si)
            #pragma unroll
            for (int ej = 0; ej < 4; ++ej)
                acc[si][ej] = (floatx4){0.f, 0.f, 0.f, 0.f};

        // ---- prologue: stage chunk 0 into buf 0
        {
            const _Float16* wg = W16sw + ((size_t)e0 << 5);
            #pragma unroll
            for (int it = 0; it < 4; ++it) {
                int o = (wv * 4 + it) * 512 + (lane << 3);
                gload16(wg + o, &Wc[0][o]);
            }
            const float* wp = wordRow + jgT * 8;
            floatx4 w0 = *(const floatx4*)wp;
            floatx4 w1 = *(const floatx4*)(wp + 4);
            const float* ip = &imgS[wv][jgT * 8];
            floatx4 i0 = *(const floatx4*)ip;
            floatx4 i1 = *(const floatx4*)(ip + 4);
            half8 t;
            t[0] = tanh_ps(i0[0] * w0[0]); t[1] = tanh_ps(i0[1] * w0[1]);
            t[2] = tanh_ps(i0[2] * w0[2]); t[3] = tanh_ps(i0[3] * w0[3]);
            t[4] = tanh_ps(i1[0] * w1[0]); t[5] = tanh_ps(i1[1] * w1[1]);
            t[6] = tanh_ps(i1[2] * w1[2]); t[7] = tanh_ps(i1[3] * w1[3]);
            *(half8*)&Tc[0][phys16(wv * CB + ciT, jgT) << 3] = t;
        }

        // ---- pipelined chunk loop: 1 barrier per chunk
        for (int kki = 0; kki < NCH; ++kki) {
            const int mb = kki & 1;
            __syncthreads();  // stage(kki) visible (drains DMA vmcnt + T lgkm); buf mb^1 free

            floatx4 w0, w1, i0, i1;
            if (kki < NCH - 1) {
                // issue next chunk's DMA + T-input loads early (latency overlapped by MFMA)
                const _Float16* wg = W16sw + (((size_t)(kki + 1)) << 14) + ((size_t)e0 << 5);
                #pragma unroll
                for (int it = 0; it < 4; ++it) {
                    int o = (wv * 4 + it) * 512 + (lane << 3);
                    gload16(wg + o, &Wc[mb ^ 1][o]);
                }
                const int kn = (kki + 1) * BK;
                const float* wp = wordRow + kn + jgT * 8;
                w0 = *(const floatx4*)wp;
                w1 = *(const floatx4*)(wp + 4);
                const float* ip = &imgS[wv][kn + jgT * 8];
                i0 = *(const floatx4*)ip;
                i1 = *(const floatx4*)(ip + 4);
            }

            // MFMA on chunk kki from buf mb
            half8 bf[4], af[4];
            #pragma unroll
            for (int ej = 0; ej < 4; ++ej)
                bf[ej] = *(const half8*)&Wc[mb][phys16(wv * 64 + ej * 16 + l15, quad) << 3];
            #pragma unroll
            for (int si = 0; si < 4; ++si)
                af[si] = *(const half8*)&Tc[mb][phys16(si * CB + l15, quad) << 3];
            #pragma unroll
            for (int si = 0; si < 4; ++si)
                #pragma unroll
                for (int ej = 0; ej < 4; ++ej)
                    acc[si][ej] = __builtin_amdgcn_mfma_f32_16x16x32_f16(
                        af[si], bf[ej], acc[si][ej], 0, 0, 0);

            if (kki < NCH - 1) {
                half8 t;
                t[0] = tanh_ps(i0[0] * w0[0]); t[1] = tanh_ps(i0[1] * w0[1]);
                t[2] = tanh_ps(i0[2] * w0[2]); t[3] = tanh_ps(i0[3] * w0[3]);
                t[4] = tanh_ps(i1[0] * w1[0]); t[5] = tanh_ps(i1[1] * w1[1]);
                t[6] = tanh_ps(i1[2] * w1[2]); t[7] = tanh_ps(i1[3] * w1[3]);
                *(half8*)&Tc[mb ^ 1][phys16(wv * CB + ciT, jgT) << 3] = t;
            }
        }

        // ---- online softmax accumulate (bias cancels; no max-sub needed)
        #pragma unroll
        for (int si = 0; si < 4; ++si) {
            if (si >= slim) break;
            #pragma unroll
            for (int ej = 0; ej < 4; ++ej) {
                float ie = imgS[si][e0 + wv * 64 + ej * 16 + l15] * INVK;
                #pragma unroll
                for (int r = 0; r < 4; ++r) {
                    float ev = __builtin_amdgcn_exp2f(acc[si][ej][r] * 1.44269504f);
                    lacc[ej][r] += ev;
                    aacc[ej][r] += ie * ev;
                }
            }
        }
    }

    // ---- writeout (C/D layout: col=l15 -> c... col maps e? col=lane&15 -> e; row=quad*4+r -> c)
    if (use_slice) {
        float* lsl = lbase + (size_t)sc * SLICE_ELEMS;
        float* asl = abase + (size_t)sc * SLICE_ELEMS;
        #pragma unroll
        for (int r = 0; r < 4; ++r) {
            int cg = c0 + quad * 4 + r;
            #pragma unroll
            for (int ej = 0; ej < 4; ++ej) {
                int eg = e0 + wv * 64 + ej * 16 + l15;
                size_t o = ((size_t)b * Cpad + cg) * D + eg;
                lsl[o] = lacc[ej][r];
                asl[o] = aacc[ej][r];
            }
        }
    } else {
        #pragma unroll
        for (int r = 0; r < 4; ++r) {
            int cg = c0 + quad * 4 + r;
            #pragma unroll
            for (int ej = 0; ej < 4; ++ej) {
                int eg = e0 + wv * 64 + ej * 16 + l15;
                atomicAdd(&lbase[((size_t)b * Cpad + cg) * D + eg], lacc[ej][r]);
                if (cg < C)
                    atomicAdd(&abase[((size_t)b * C + cg) * D + eg], aacc[ej][r]);
            }
        }
    }
}

__global__ void finalize_k(const float* __restrict__ lbase, const float* __restrict__ abase,
                           float* __restrict__ out, int use_slice) {
    int o = blockIdx.x * blockDim.x + threadIdx.x;
    if (o >= 2 * C * D) return;
    int b = o / (C * D);
    int rem = o - b * (C * D);
    int c = rem >> 9;
    int e = rem & (D - 1);
    size_t p = ((size_t)b * Cpad + c) * D + e;
    if (use_slice) {
        float l = 0.f, a = 0.f;
        #pragma unroll
        for (int scn = 0; scn < SCH; ++scn) {
            l += lbase[(size_t)scn * SLICE_ELEMS + p];
            a += abase[(size_t)scn * SLICE_ELEMS + p];
        }
        out[o] = a / l;
    } else {
        out[o] = out[o] / lbase[p];
    }
}

} // namespace

extern "C" void kernel_launch(void* const* d_in, const int* in_sizes, int n_in,
                              void* d_out, int out_size, void* d_ws, size_t ws_size,
                              hipStream_t stream) {
    const float* img  = (const float*)d_in[0];
    const float* word = (const float*)d_in[1];
    const float* fw   = (const float*)d_in[2];
    // d_in[3] = fc3_b: constant over softmax axis s -> cancels exactly.
    float* out = (float*)d_out;
    char* ws = (char*)d_ws;

    _Float16* W16sw = (_Float16*)ws;
    const int use_slice = (ws_size >= SLICE_NEED) ? 1 : 0;

    hipLaunchKernelGGL(prep_w16sw, dim3(128), dim3(256), 0, stream, fw, W16sw);

    float *lbase, *abase;
    if (use_slice) {
        lbase = (float*)(ws + LA_OFF);
        abase = (float*)(ws + LA_OFF + SL_BYTES);
    } else {
        lbase = (float*)(ws + LA_OFF);
        abase = out;
        hipMemsetAsync(lbase, 0, L_BYTES, stream);
        hipMemsetAsync(out, 0, (size_t)2 * C * D * 4, stream);
    }

    hipLaunchKernelGGL(semdec_mfma, dim3(64, 4, SCH), dim3(TPB), 0, stream,
                       img, word, W16sw, lbase, abase, use_slice);

    hipLaunchKernelGGL(finalize_k, dim3((2 * C * D + 255) / 256), dim3(256), 0, stream,
                       lbase, abase, out, use_slice);
}